// Round 8
// baseline (2603.426 us; speedup 1.0000x reference)
//
#include <hip/hip_runtime.h>

#define TT 1024
#define DD 768
#define FFD 3072
#define NH 12
#define NL 12
#define HDIM 64
#define VOC 50257
#define BT 2048  // B*T

typedef __attribute__((ext_vector_type(8))) __bf16 bf16x8;
typedef __attribute__((ext_vector_type(4))) float f32x4;
typedef __attribute__((ext_vector_type(4))) unsigned short u16x4;
typedef unsigned short u16;

static __device__ __forceinline__ u16 f2bf(float f) {
  unsigned int u = __float_as_uint(f);
  u += 0x7FFF + ((u >> 16) & 1);  // round-to-nearest-even
  return (u16)(u >> 16);
}

// async global->LDS, 16B per lane; LDS dest = wave-uniform base + lane*16
static __device__ __forceinline__ void load_lds16(const u16* g, u16* l) {
  __builtin_amdgcn_global_load_lds(
      (const __attribute__((address_space(1))) unsigned int*)g,
      (__attribute__((address_space(3))) unsigned int*)l, 16, 0, 0);
}

// ---------------------------------------------------------------- converts
__global__ __launch_bounds__(256) void transpose_convert(
    const float* __restrict__ in, u16* __restrict__ out, int R, int C) {
  __shared__ float tile[32][33];
  const long long zo = (long long)blockIdx.z * R * C;
  const int c0 = blockIdx.x * 32, r0 = blockIdx.y * 32;
  const int tx = threadIdx.x & 31, ty = threadIdx.x >> 5;
#pragma unroll
  for (int i = 0; i < 32; i += 8)
    tile[ty + i][tx] = in[zo + (long long)(r0 + ty + i) * C + c0 + tx];
  __syncthreads();
#pragma unroll
  for (int i = 0; i < 32; i += 8)
    out[zo + (long long)(c0 + ty + i) * R + r0 + tx] = f2bf(tile[tx][ty + i]);
}

__global__ void convert_bf16(const float* __restrict__ in, u16* __restrict__ out,
                             long long n) {
  long long i = (long long)blockIdx.x * 256 + threadIdx.x;
  const long long stride = (long long)gridDim.x * 256;
  for (; i < n; i += stride) out[i] = f2bf(in[i]);
}

// ---------------------------------------------------------------- embed
__global__ __launch_bounds__(256) void embed_kernel(
    const int* __restrict__ tokens, const float* __restrict__ tokE,
    const float* __restrict__ posE, float* __restrict__ x) {
  const int row = blockIdx.x;        // b*1024 + t
  const int t = row & (TT - 1);
  const int tok = tokens[row];
  const int tid = threadIdx.x;
#pragma unroll
  for (int c = 0; c < 3; ++c) {
    int d = tid + c * 256;
    x[(long long)row * DD + d] = tokE[(long long)tok * DD + d] + posE[(long long)t * DD + d];
  }
}

// ---------------------------------------------------------------- layernorm (+ split-K partial fold)
// nsum>0: x[row] += sum of nsum partial slices (pp), written back to x, then LN.
__global__ __launch_bounds__(256) void ln_sum(
    float* __restrict__ x, const float* __restrict__ pp, int nsum,
    const float* __restrict__ w, const float* __restrict__ b,
    u16* __restrict__ out) {
  const int row = blockIdx.x;
  const long long base = (long long)row * DD;
  const int tid = threadIdx.x;
  float v[3];
  float s = 0.f, s2 = 0.f;
#pragma unroll
  for (int c = 0; c < 3; ++c) {
    const int d = tid + c * 256;
    float t = x[base + d];
    for (int q = 0; q < nsum; ++q) t += pp[(long long)q * BT * DD + base + d];
    if (nsum) x[base + d] = t;
    v[c] = t; s += t; s2 += t * t;
  }
  for (int off = 32; off; off >>= 1) {
    s += __shfl_down(s, off, 64);
    s2 += __shfl_down(s2, off, 64);
  }
  __shared__ float rs[8];
  if ((tid & 63) == 0) { rs[tid >> 6] = s; rs[4 + (tid >> 6)] = s2; }
  __syncthreads();
  s = rs[0] + rs[1] + rs[2] + rs[3];
  s2 = rs[4] + rs[5] + rs[6] + rs[7];
  const float mu = s * (1.0f / DD);
  const float var = s2 * (1.0f / DD) - mu * mu;
  const float inv = rsqrtf(var + 1e-5f);
  u16* o = out + base;
#pragma unroll
  for (int c = 0; c < 3; ++c) {
    int d = tid + c * 256;
    o[d] = f2bf((v[c] - mu) * inv * w[d] + b[d]);
  }
}

// ---------------------------------------------------------------- flash attention
// One block per (z, q-tile of 64). 4 waves, wave w owns q rows [w*16, w*16+16).
// Swapped QK^T: S^T = mfma(K_frag, Q_frag) -> lane owns one q-column; row-softmax
// = 16 in-lane values + shfl_xor(16,32) across quads. P goes through a per-wave
// padded LDS scratch (pitch 72) to reach the MFMA A-layout. K/V/Q tiles staged
// via global_load_lds with both-sides XOR swizzle chunk^=(row>>1)&7.
// K/V double-buffered; one barrier per kv-tile.
__global__ __launch_bounds__(256, 3) void flash_attn(
    const u16* __restrict__ qkv, const u16* __restrict__ vT,
    u16* __restrict__ attn) {
  __shared__ __align__(16) u16 Qs[64 * 64];
  __shared__ __align__(16) u16 Ks0[64 * 64];
  __shared__ __align__(16) u16 Ks1[64 * 64];
  __shared__ __align__(16) u16 Vs0[64 * 64];
  __shared__ __align__(16) u16 Vs1[64 * 64];
  __shared__ __align__(16) u16 Ps[4 * 16 * 72];

  const int id = blockIdx.x;            // 384 = 16 q-tiles * 24 z
  const int qt = 15 - id / 24;          // heavy q-tiles dispatched first
  const int z = id % 24;
  const int b = z / NH, h = z - (z / NH) * NH;
  const int q0 = qt * 64;

  const int tid = threadIdx.x;
  const int lane = tid & 63;
  const int wave = __builtin_amdgcn_readfirstlane(tid >> 6);
  const int mf = lane & 15;
  const int quad = lane >> 4;

  // staging: wave w fills tile rows [w*16, w*16+16), 2 issues of 1024B
  const int srow = wave * 16 + (lane >> 3);
  const int srow1 = srow + 8;
  const int sch0 = (((lane & 7) ^ ((srow >> 1) & 7))) * 8;   // swizzled col (elems)
  const int sch1 = (((lane & 7) ^ ((srow1 >> 1) & 7))) * 8;
  const int lb = wave * 1024;  // wave-uniform LDS base (elems)

  const u16* qk_base = qkv + (long long)b * TT * 2304 + h * 64;

  auto stageKV = [&](u16* Kd, u16* Vd, int kv0) {
    load_lds16(qk_base + (long long)(kv0 + srow) * 2304 + 768 + sch0, Kd + lb);
    load_lds16(qk_base + (long long)(kv0 + srow1) * 2304 + 768 + sch1, Kd + lb + 512);
    load_lds16(vT + (long long)(z * 64 + srow) * 1024 + kv0 + sch0, Vd + lb);
    load_lds16(vT + (long long)(z * 64 + srow1) * 1024 + kv0 + sch1, Vd + lb + 512);
  };

  // stage Q + first K/V
  load_lds16(qk_base + (long long)(q0 + srow) * 2304 + sch0, Qs + lb);
  load_lds16(qk_base + (long long)(q0 + srow1) * 2304 + sch1, Qs + lb + 512);
  stageKV(Ks0, Vs0, 0);
  __syncthreads();

  // Q fragments (B-operand: row q = wave*16+mf, k = ks*32+quad*8)
  bf16x8 qfr[2];
  {
    const int r = wave * 16 + mf;
    const int sw = (r >> 1) & 7;
#pragma unroll
    for (int ks = 0; ks < 2; ++ks)
      qfr[ks] = *(const bf16x8*)(Qs + r * 64 + (((ks * 4 + quad) ^ sw) * 8));
  }

  f32x4 oacc[4] = {};
  float mrun = -1e30f, lrun = 0.f;
  u16 *Kc = Ks0, *Vc = Vs0, *Kn = Ks1, *Vn = Vs1;

  for (int t = 0; t <= qt; ++t) {
    if (t < qt) stageKV(Kn, Vn, (t + 1) * 64);
    const int diag = (t == qt);

    // S^T[kv][q] = sum_d K[kv][d] * Q[q][d]
    f32x4 sacc[4] = {};
#pragma unroll
    for (int ks = 0; ks < 2; ++ks)
#pragma unroll
      for (int i = 0; i < 4; ++i) {
        const int r = i * 16 + mf;
        bf16x8 kfr = *(const bf16x8*)(Kc + r * 64 + (((ks * 4 + quad) ^ ((r >> 1) & 7)) * 8));
        sacc[i] = __builtin_amdgcn_mfma_f32_16x16x32_bf16(kfr, qfr[ks], sacc[i], 0, 0, 0);
      }

    // online softmax over this tile (lane owns q = wave*16+mf; kv = i*16+quad*4+r)
    float pv[4][4];
    float tmax = -1e30f;
#pragma unroll
    for (int i = 0; i < 4; ++i)
#pragma unroll
      for (int r = 0; r < 4; ++r) {
        float v = sacc[i][r] * 0.125f;
        if (diag) {
          const int kvl = i * 16 + quad * 4 + r;
          if (kvl > wave * 16 + mf) v = -1e30f;
        }
        pv[i][r] = v;
        tmax = fmaxf(tmax, v);
      }
    tmax = fmaxf(tmax, __shfl_xor(tmax, 16, 64));
    tmax = fmaxf(tmax, __shfl_xor(tmax, 32, 64));
    const float mnew = fmaxf(mrun, tmax);
    const float fac = __expf(mrun - mnew);  // first tile: exp(-huge) = 0
    float lsum = 0.f;
#pragma unroll
    for (int i = 0; i < 4; ++i)
#pragma unroll
      for (int r = 0; r < 4; ++r) {
        float e = __expf(pv[i][r] - mnew);
        pv[i][r] = e;
        lsum += e;
      }
    lsum += __shfl_xor(lsum, 16, 64);
    lsum += __shfl_xor(lsum, 32, 64);
    lrun = lrun * fac + lsum;
    mrun = mnew;

    // rescale O: factor for q-row (quad*4+r) lives at lane (same quad, mf=quad*4+r)
    float fo[4];
#pragma unroll
    for (int r = 0; r < 4; ++r) fo[r] = __shfl(fac, (lane & 48) | (quad * 4 + r), 64);
#pragma unroll
    for (int j = 0; j < 4; ++j)
#pragma unroll
      for (int r = 0; r < 4; ++r) oacc[j][r] *= fo[r];

    // P -> per-wave LDS scratch [16 q][72 pitch] (bf16)
#pragma unroll
    for (int i = 0; i < 4; ++i) {
      u16x4 pk;
#pragma unroll
      for (int r = 0; r < 4; ++r) pk[r] = f2bf(pv[i][r]);
      *(u16x4*)(Ps + wave * 1152 + mf * 72 + i * 16 + quad * 4) = pk;
    }
    // PV: O[q][d] += sum_kv P[q][kv] * V^T[d][kv]
#pragma unroll
    for (int ks = 0; ks < 2; ++ks) {
      bf16x8 pfr = *(const bf16x8*)(Ps + wave * 1152 + mf * 72 + ks * 32 + quad * 8);
#pragma unroll
      for (int j = 0; j < 4; ++j) {
        const int r = j * 16 + mf;
        bf16x8 vfr = *(const bf16x8*)(Vc + r * 64 + (((ks * 4 + quad) ^ ((r >> 1) & 7)) * 8));
        oacc[j] = __builtin_amdgcn_mfma_f32_16x16x32_bf16(pfr, vfr, oacc[j], 0, 0, 0);
      }
    }
    __syncthreads();  // all waves done with cur bufs; next bufs' loads drained
    u16* tk = Kc; Kc = Kn; Kn = tk;
    u16* tv = Vc; Vc = Vn; Vn = tv;
  }

  // epilogue: O / l ; output lane holds d = j*16+mf, q = wave*16 + quad*4 + r
  const float linv = 1.0f / lrun;
  float li[4];
#pragma unroll
  for (int r = 0; r < 4; ++r) li[r] = __shfl(linv, (lane & 48) | (quad * 4 + r), 64);
#pragma unroll
  for (int j = 0; j < 4; ++j)
#pragma unroll
    for (int r = 0; r < 4; ++r) {
      const int q = q0 + wave * 16 + quad * 4 + r;
      const int d = j * 16 + mf;
      attn[(long long)(b * TT + q) * 768 + h * 64 + d] = f2bf(oacc[j][r] * li[r]);
    }
}

// ---------------------------------------------------------------- GEMM (NT)
// C[z][m][n] = sum_k A[z][m][k] * B[z][n][k]  (+ epilogue)
// 128x128 tile, BK=32, 2-phase double-buffered pipeline.
// Staging via global_load_lds dwordx4 (linear LDS dest). Bank-conflict fix
// (rule 21): 16B-chunk XOR swizzle chunk^=(row>>1)&3 on global source AND
// ds_read addresses. xcdChunk: bijective chunked XCD swizzle (T1).
// kSplit>1: blockIdx.z = K-slice; EPI_SPLITK_PART writes plain partials to
// Cout + z*M*ldc (bias folded into slice 0); the next ln_sum folds them.
// NOTE (round-6 lesson): nontemporal stores on the MFMA fragment epilogue
// REGRESS 1.75x — 64B scattered segments bypass L2 write-combining.
enum { EPI_F32 = 0, EPI_BF16_BIAS = 1, EPI_BF16_BIAS_GELU = 2,
       EPI_BF16 = 4, EPI_QKV = 5, EPI_SPLITK_PART = 6 };

template <int EPI>
__global__ __launch_bounds__(256, 3) void gemm_nt(
    const u16* __restrict__ A, const u16* __restrict__ Bm,
    const float* __restrict__ bias,
    void* __restrict__ Cout, u16* __restrict__ vtAux,
    int M, int N, int K, int lda, int ldb, int ldc,
    long long aHi, long long aLo, long long bHi, long long bLo,
    long long cHi, long long cLo, int Hdiv, int swapxy,
    int xcdChunk, int kSplit) {
  __shared__ __align__(16) u16 As0[128 * 32];
  __shared__ __align__(16) u16 As1[128 * 32];
  __shared__ __align__(16) u16 Bs0[128 * 32];
  __shared__ __align__(16) u16 Bs1[128 * 32];
  const int z = blockIdx.z;
  int zb = 0, zh = 0;
  long long koff = 0;
  if (kSplit > 1) {          // z = K-slice index (batch/head decomposition off)
    const int slice = K / kSplit;
    koff = (long long)z * slice;
    K = slice;
  } else {
    zb = z / Hdiv; zh = z - zb * Hdiv;
  }
  const u16* Ab = A + zb * aHi + zh * aLo + koff;
  const u16* Bb = Bm + zb * bHi + zh * bLo + koff;
  const long long cOff = (long long)zb * cHi + (long long)zh * cLo;

  int rx = blockIdx.x, ry = blockIdx.y;
  if (xcdChunk) {  // per-XCD contiguous work chunks (bijective: nwg%8==0)
    const int id = ry * gridDim.x + rx;
    const int w = (id & 7) * xcdChunk + (id >> 3);
    rx = w % gridDim.x;
    ry = w / gridDim.x;
  }
  const int bx = swapxy ? ry : rx;  // swapxy=1: M fastest for B-panel reuse
  const int by = swapxy ? rx : ry;
  const int m0 = by * 128;
  const int n0 = bx * 128;

  const int tid = threadIdx.x;
  const int lane = tid & 63;
  const int wave = __builtin_amdgcn_readfirstlane(tid >> 6);
  const int wm = (wave >> 1) * 64;
  const int wn = (wave & 1) * 64;
  const int mf = lane & 15;
  const int quad = lane >> 4;

  // ---- staging geometry: wave w fills tile rows [w*32, w*32+32)
  const int sr0 = wave * 32 + (lane >> 2);
  const int sr1 = sr0 + 16;
  const int sc0 = ((lane & 3) ^ ((sr0 >> 1) & 3)) * 8;  // swizzled source col
  const int sc1 = ((lane & 3) ^ ((sr1 >> 1) & 3)) * 8;
  int br0 = n0 + sr0; if (br0 >= N) br0 = N - 1;
  int br1 = n0 + sr1; if (br1 >= N) br1 = N - 1;
  const u16* agp0 = Ab + (long long)(m0 + sr0) * lda + sc0;  // M always %128==0
  const u16* agp1 = Ab + (long long)(m0 + sr1) * lda + sc1;
  const u16* bgp0 = Bb + (long long)br0 * ldb + sc0;
  const u16* bgp1 = Bb + (long long)br1 * ldb + sc1;
  const int woff = wave * 1024;

  auto stage = [&](u16* Ad, u16* Bd, int kk) {
    load_lds16(agp0 + kk, Ad + woff);
    load_lds16(agp1 + kk, Ad + woff + 512);
    load_lds16(bgp0 + kk, Bd + woff);
    load_lds16(bgp1 + kk, Bd + woff + 512);
  };

  // ---- fragment read offsets (swizzled, constant over K-loop)
  int aoff[4], boff[4];
#pragma unroll
  for (int i = 0; i < 4; ++i) {
    const int ar = wm + i * 16 + mf;
    aoff[i] = ar * 32 + ((quad ^ ((ar >> 1) & 3)) * 8);
    const int br = wn + i * 16 + mf;
    boff[i] = br * 32 + ((quad ^ ((br >> 1) & 3)) * 8);
  }

  f32x4 acc[4][4] = {};

  auto compute = [&](const u16* Asb, const u16* Bsb) {
    bf16x8 afr[4], bfr[4];
#pragma unroll
    for (int i = 0; i < 4; ++i) afr[i] = *(const bf16x8*)(Asb + aoff[i]);
#pragma unroll
    for (int j = 0; j < 4; ++j) bfr[j] = *(const bf16x8*)(Bsb + boff[j]);
#pragma unroll
    for (int i = 0; i < 4; ++i)
#pragma unroll
      for (int j = 0; j < 4; ++j)
        acc[i][j] = __builtin_amdgcn_mfma_f32_16x16x32_bf16(afr[i], bfr[j], acc[i][j], 0, 0, 0);
  };

  // 2-phase pipeline, unrolled x2 (all K here have an even number of 32-steps)
  stage(As0, Bs0, 0);
  __syncthreads();
  for (int k0 = 0; k0 < K; k0 += 64) {
    if (k0 + 32 < K) stage(As1, Bs1, k0 + 32);
    compute(As0, Bs0);
    __syncthreads();
    if (k0 + 64 < K) stage(As0, Bs0, k0 + 64);
    compute(As1, Bs1);
    __syncthreads();
  }

#pragma unroll
  for (int j = 0; j < 4; ++j) {
    const int col = n0 + wn + j * 16 + mf;
    if (col >= N) continue;
    float bv = 0.0f;
    if (EPI == EPI_BF16_BIAS || EPI == EPI_BF16_BIAS_GELU || EPI == EPI_QKV)
      bv = bias[col];
    if (EPI == EPI_SPLITK_PART && z == 0) bv = bias[col];  // bias once per output
    if (EPI == EPI_QKV && col >= 1536) {
      // V columns: write transposed into vT[(b*NH+h)*64+d][t], packed x4
      const int hd = col - 1536;
#pragma unroll
      for (int i = 0; i < 4; ++i) {
        const int t0 = m0 + wm + i * 16 + quad * 4;  // 4 consecutive t
        u16x4 pk;
#pragma unroll
        for (int r = 0; r < 4; ++r) pk[r] = f2bf(acc[i][j][r] + bv);
        const int b_ = t0 >> 10;
        const long long vi =
            ((long long)((b_ * NH + (hd >> 6)) * 64 + (hd & 63))) * 1024 + (t0 & 1023);
        *(u16x4*)(vtAux + vi) = pk;
      }
      continue;
    }
#pragma unroll
    for (int i = 0; i < 4; ++i) {
#pragma unroll
      for (int r = 0; r < 4; ++r) {
        const int row = m0 + wm + i * 16 + quad * 4 + r;
        float v = acc[i][j][r] + bv;
        if (EPI == EPI_BF16_BIAS_GELU) {
          float u = v + 0.044715f * v * v * v;
          v = 0.5f * v * (1.0f + tanhf(0.7978845608028654f * u));
        }
        if (EPI == EPI_SPLITK_PART) {
          ((float*)Cout)[(long long)z * M * ldc + (long long)row * ldc + col] = v;
        } else {
          const long long ci = cOff + (long long)row * ldc + col;
          if (EPI == EPI_F32) {
            ((float*)Cout)[ci] = v;
          } else {
            ((u16*)Cout)[ci] = f2bf(v);
          }
        }
      }
    }
  }
}

// ---------------------------------------------------------------- lm_head GEMM
// 256x256 tile, 512 threads / 8 waves (2M x 4N), BK=32, 2-phase pipeline.
// Per K-step: 32 MFMA / 4 staging issues / 12 ds_read_b128 -> 2x the MFMA
// density of the 128^2 tile at the same per-thread staging cost (R5's 256-thr
// BM=256 failed on occupancy; 512-thr keeps 8 resident waves/CU).
// LDS 64 KB; ~190 VGPR -> 2 waves/SIMD. Same both-sides XOR chunk swizzle.
// Grid (8, 197): M fastest; bijective XCD chunking over 1576 blocks.
__global__ __launch_bounds__(512, 2) void gemm_lmhead(
    const u16* __restrict__ A, const u16* __restrict__ Bm,
    float* __restrict__ C, int N) {
  __shared__ __align__(16) u16 As[2][256 * 32];
  __shared__ __align__(16) u16 Bs[2][256 * 32];

  const int id = blockIdx.y * 8 + blockIdx.x;     // launch order: x fastest
  const int w = (id & 7) * 197 + (id >> 3);       // per-XCD contiguous chunks
  const int m0 = (w & 7) * 256;                   // M fastest within chunk
  const int n0 = (w >> 3) * 256;

  const int tid = threadIdx.x;
  const int lane = tid & 63;
  const int wave = __builtin_amdgcn_readfirstlane(tid >> 6);
  const int wr = wave >> 2;   // 0..1 -> rows [wr*128, +128)
  const int wc = wave & 3;    // 0..3 -> cols [wc*64, +64)
  const int mf = lane & 15;
  const int quad = lane >> 4;

  // staging: 4 lanes/row (64B rows); wave covers 16 rows per issue;
  // issue 0 -> tile rows [wave*16, +16), issue 1 -> +128.
  const int srow0 = wave * 16 + (lane >> 2);
  const int srow1 = srow0 + 128;
  const int sc0 = ((lane & 3) ^ ((srow0 >> 1) & 3)) * 8;  // pre-swizzled source col
  const int sc1 = ((lane & 3) ^ ((srow1 >> 1) & 3)) * 8;
  const u16* agp0 = A + (long long)(m0 + srow0) * 768 + sc0;  // M=2048 %256==0
  const u16* agp1 = A + (long long)(m0 + srow1) * 768 + sc1;
  int br0 = n0 + srow0; if (br0 >= N) br0 = N - 1;  // vocab tail clamp
  int br1 = n0 + srow1; if (br1 >= N) br1 = N - 1;
  const u16* bgp0 = Bm + (long long)br0 * 768 + sc0;
  const u16* bgp1 = Bm + (long long)br1 * 768 + sc1;
  const int woff0 = wave * 16 * 32;          // elems; lane adds lane*8 (linear)
  const int woff1 = (128 + wave * 16) * 32;

  auto stage = [&](int buf, int kk) {
    load_lds16(agp0 + kk, &As[buf][woff0]);
    load_lds16(agp1 + kk, &As[buf][woff1]);
    load_lds16(bgp0 + kk, &Bs[buf][woff0]);
    load_lds16(bgp1 + kk, &Bs[buf][woff1]);
  };

  // fragment read offsets (swizzled, constant over K-loop)
  int aoff[8], boff[4];
#pragma unroll
  for (int i = 0; i < 8; ++i) {
    const int ar = wr * 128 + i * 16 + mf;
    aoff[i] = ar * 32 + ((quad ^ ((ar >> 1) & 3)) * 8);
  }
#pragma unroll
  for (int j = 0; j < 4; ++j) {
    const int br = wc * 64 + j * 16 + mf;
    boff[j] = br * 32 + ((quad ^ ((br >> 1) & 3)) * 8);
  }

  f32x4 acc[8][4] = {};

  auto compute = [&](int buf) {
    bf16x8 afr[8], bfr[4];
#pragma unroll
    for (int j = 0; j < 4; ++j) bfr[j] = *(const bf16x8*)(&Bs[buf][boff[j]]);
#pragma unroll
    for (int i = 0; i < 8; ++i) afr[i] = *(const bf16x8*)(&As[buf][aoff[i]]);
#pragma unroll
    for (int i = 0; i < 8; ++i)
#pragma unroll
      for (int j = 0; j < 4; ++j)
        acc[i][j] = __builtin_amdgcn_mfma_f32_16x16x32_bf16(afr[i], bfr[j], acc[i][j], 0, 0, 0);
  };

  // 2-phase pipeline; K=768 -> 12 double-steps (even)
  stage(0, 0);
  __syncthreads();
  for (int k0 = 0; k0 < 768; k0 += 64) {
    if (k0 + 32 < 768) stage(1, k0 + 32);
    compute(0);
    __syncthreads();
    if (k0 + 64 < 768) stage(0, k0 + 64);
    compute(1);
    __syncthreads();
  }

#pragma unroll
  for (int j = 0; j < 4; ++j) {
    const int col = n0 + wc * 64 + j * 16 + mf;
    if (col >= N) continue;
#pragma unroll
    for (int i = 0; i < 8; ++i)
#pragma unroll
      for (int r = 0; r < 4; ++r) {
        const int row = m0 + wr * 128 + i * 16 + quad * 4 + r;
        C[(long long)row * N + col] = acc[i][j][r];
      }
  }
}

// ---------------------------------------------------------------- launch
extern "C" void kernel_launch(void* const* d_in, const int* in_sizes, int n_in,
                              void* d_out, int out_size, void* d_ws, size_t ws_size,
                              hipStream_t stream) {
  const int* tokens      = (const int*)d_in[0];
  const float* tok_embed = (const float*)d_in[1];
  const float* pos_embed = (const float*)d_in[2];
  const float* qkv_w     = (const float*)d_in[3];
  const float* qkv_b     = (const float*)d_in[4];
  const float* proj_w    = (const float*)d_in[5];
  const float* proj_b    = (const float*)d_in[6];
  const float* ln1_w     = (const float*)d_in[7];
  const float* ln1_b     = (const float*)d_in[8];
  const float* ln2_w     = (const float*)d_in[9];
  const float* ln2_b     = (const float*)d_in[10];
  const float* fc1_w     = (const float*)d_in[11];
  const float* fc1_b     = (const float*)d_in[12];
  const float* fc2_w     = (const float*)d_in[13];
  const float* fc2_b     = (const float*)d_in[14];
  const float* lnf_w     = (const float*)d_in[15];
  const float* lnf_b     = (const float*)d_in[16];

  if (ws_size < 440u * 1024u * 1024u) return;  // scratch guard

  char* p = (char*)d_ws;
  auto alloc = [&](size_t bytes) {
    void* r = (void*)p;
    p += (bytes + 255) & ~(size_t)255;
    return r;
  };
  u16* wq   = (u16*)alloc((size_t)NL * 2304 * 768 * 2);  // qkv_w^T  [L][2304][768]
  u16* wp   = (u16*)alloc((size_t)NL * 768 * 768 * 2);   // proj_w^T [L][768][768]
  u16* w1   = (u16*)alloc((size_t)NL * 3072 * 768 * 2);  // fc1_w^T  [L][3072][768]
  u16* w2   = (u16*)alloc((size_t)NL * 768 * 3072 * 2);  // fc2_w^T  [L][768][3072]
  u16* te   = (u16*)alloc((size_t)VOC * 768 * 2);        // tok_embed bf16 [V][768]
  float* x  = (float*)alloc((size_t)BT * 768 * 4);       // residual stream fp32
  u16* hbuf = (u16*)alloc((size_t)BT * 768 * 2);         // LN output bf16
  u16* qkv  = (u16*)alloc((size_t)BT * 2304 * 2);
  u16* vT   = (u16*)alloc((size_t)24 * 64 * 1024 * 2);   // [b,h][64][1024]
  u16* attn = (u16*)alloc((size_t)BT * 768 * 2);
  u16* ff   = (u16*)alloc((size_t)BT * 3072 * 2);
  u16* xf   = (u16*)alloc((size_t)BT * 768 * 2);
  float* pp = (float*)alloc((size_t)4 * BT * 768 * 4);   // split-K partials

  // weight conversion (per call; ws is re-poisoned before every timed launch)
  transpose_convert<<<dim3(2304 / 32, 768 / 32, NL), 256, 0, stream>>>(qkv_w, wq, 768, 2304);
  transpose_convert<<<dim3(768 / 32, 768 / 32, NL), 256, 0, stream>>>(proj_w, wp, 768, 768);
  transpose_convert<<<dim3(3072 / 32, 768 / 32, NL), 256, 0, stream>>>(fc1_w, w1, 768, 3072);
  transpose_convert<<<dim3(768 / 32, 3072 / 32, NL), 256, 0, stream>>>(fc2_w, w2, 3072, 768);
  convert_bf16<<<4096, 256, 0, stream>>>(tok_embed, te, (long long)VOC * 768);
  embed_kernel<<<BT, 256, 0, stream>>>(tokens, tok_embed, pos_embed, x);

  for (int l = 0; l < NL; ++l) {
    // ln1: fold previous layer's fc2 partials (4 slices) into x, then LN
    ln_sum<<<BT, 256, 0, stream>>>(x, pp, l == 0 ? 0 : 4,
                                   ln1_w + l * 768, ln1_b + l * 768, hbuf);
    // qkv GEMM; V columns (>=1536) go transposed straight into vT
    gemm_nt<EPI_QKV><<<dim3(2304 / 128, BT / 128, 1), 256, 0, stream>>>(
        hbuf, wq + (size_t)l * 2304 * 768, qkv_b + l * 2304, qkv, vT,
        BT, 2304, 768, 768, 768, 2304, 0, 0, 0, 0, 0, 0, 1, 0, 288 / 8, 1);
    // fused flash attention: QK^T + causal online-softmax + PV in one pass
    flash_attn<<<384, 256, 0, stream>>>(qkv, vT, attn);
    // proj: split-K x3 (288 blocks, full-chip), plain partial writes
    gemm_nt<EPI_SPLITK_PART><<<dim3(768 / 128, BT / 128, 3), 256, 0, stream>>>(
        attn, wp + (size_t)l * 768 * 768, proj_b + l * 768, pp, nullptr,
        BT, 768, 768, 768, 768, 768, 0, 0, 0, 0, 0, 0, 1, 0, 96 / 8, 3);
    // ln2: x += proj partials (3 slices), then LN
    ln_sum<<<BT, 256, 0, stream>>>(x, pp, 3,
                                   ln2_w + l * 768, ln2_b + l * 768, hbuf);
    gemm_nt<EPI_BF16_BIAS_GELU><<<dim3(3072 / 128, BT / 128, 1), 256, 0, stream>>>(
        hbuf, w1 + (size_t)l * 3072 * 768, fc1_b + l * 3072, ff, nullptr,
        BT, 3072, 768, 768, 768, 3072, 0, 0, 0, 0, 0, 0, 1, 0, 384 / 8, 1);
    // fc2: split-K x4 (384 blocks), plain partial writes
    gemm_nt<EPI_SPLITK_PART><<<dim3(768 / 128, BT / 128, 4), 256, 0, stream>>>(
        ff, w2 + (size_t)l * 768 * 3072, fc2_b + l * 768, pp, nullptr,
        BT, 768, 3072, 3072, 3072, 768, 0, 0, 0, 0, 0, 0, 1, 0, 96 / 8, 4);
  }
  // final LN folds the last fc2 partials
  ln_sum<<<BT, 256, 0, stream>>>(x, pp, 4, lnf_w, lnf_b, xf);
  // lm_head: 256x256 tile, 512 threads, M fastest + XCD chunking (1576 = 8*197)
  gemm_lmhead<<<dim3(8, 197), 512, 0, stream>>>(xf, te, (float*)d_out, VOC);
}

// Round 9
// 2430.677 us; speedup vs baseline: 1.0711x; 1.0711x over previous
//
#include <hip/hip_runtime.h>

#define TT 1024
#define DD 768
#define FFD 3072
#define NH 12
#define NL 12
#define HDIM 64
#define VOC 50257
#define BT 2048  // B*T

typedef __attribute__((ext_vector_type(8))) __bf16 bf16x8;
typedef __attribute__((ext_vector_type(4))) float f32x4;
typedef __attribute__((ext_vector_type(4))) unsigned short u16x4;
typedef unsigned short u16;

static __device__ __forceinline__ u16 f2bf(float f) {
  unsigned int u = __float_as_uint(f);
  u += 0x7FFF + ((u >> 16) & 1);  // round-to-nearest-even
  return (u16)(u >> 16);
}

// async global->LDS, 16B per lane; LDS dest = wave-uniform base + lane*16
static __device__ __forceinline__ void load_lds16(const u16* g, u16* l) {
  __builtin_amdgcn_global_load_lds(
      (const __attribute__((address_space(1))) unsigned int*)g,
      (__attribute__((address_space(3))) unsigned int*)l, 16, 0, 0);
}

// ---------------------------------------------------------------- converts
__global__ __launch_bounds__(256) void transpose_convert(
    const float* __restrict__ in, u16* __restrict__ out, int R, int C) {
  __shared__ float tile[32][33];
  const long long zo = (long long)blockIdx.z * R * C;
  const int c0 = blockIdx.x * 32, r0 = blockIdx.y * 32;
  const int tx = threadIdx.x & 31, ty = threadIdx.x >> 5;
#pragma unroll
  for (int i = 0; i < 32; i += 8)
    tile[ty + i][tx] = in[zo + (long long)(r0 + ty + i) * C + c0 + tx];
  __syncthreads();
#pragma unroll
  for (int i = 0; i < 32; i += 8)
    out[zo + (long long)(c0 + ty + i) * R + r0 + tx] = f2bf(tile[tx][ty + i]);
}

__global__ void convert_bf16(const float* __restrict__ in, u16* __restrict__ out,
                             long long n) {
  long long i = (long long)blockIdx.x * 256 + threadIdx.x;
  const long long stride = (long long)gridDim.x * 256;
  for (; i < n; i += stride) out[i] = f2bf(in[i]);
}

// ---------------------------------------------------------------- embed
__global__ __launch_bounds__(256) void embed_kernel(
    const int* __restrict__ tokens, const float* __restrict__ tokE,
    const float* __restrict__ posE, float* __restrict__ x) {
  const int row = blockIdx.x;        // b*1024 + t
  const int t = row & (TT - 1);
  const int tok = tokens[row];
  const int tid = threadIdx.x;
#pragma unroll
  for (int c = 0; c < 3; ++c) {
    int d = tid + c * 256;
    x[(long long)row * DD + d] = tokE[(long long)tok * DD + d] + posE[(long long)t * DD + d];
  }
}

// ---------------------------------------------------------------- layernorm (+ split-K partial fold)
// nsum>0: x[row] += sum of nsum partial slices (pp), written back to x, then LN.
__global__ __launch_bounds__(256) void ln_sum(
    float* __restrict__ x, const float* __restrict__ pp, int nsum,
    const float* __restrict__ w, const float* __restrict__ b,
    u16* __restrict__ out) {
  const int row = blockIdx.x;
  const long long base = (long long)row * DD;
  const int tid = threadIdx.x;
  float v[3];
  float s = 0.f, s2 = 0.f;
#pragma unroll
  for (int c = 0; c < 3; ++c) {
    const int d = tid + c * 256;
    float t = x[base + d];
    for (int q = 0; q < nsum; ++q) t += pp[(long long)q * BT * DD + base + d];
    if (nsum) x[base + d] = t;
    v[c] = t; s += t; s2 += t * t;
  }
  for (int off = 32; off; off >>= 1) {
    s += __shfl_down(s, off, 64);
    s2 += __shfl_down(s2, off, 64);
  }
  __shared__ float rs[8];
  if ((tid & 63) == 0) { rs[tid >> 6] = s; rs[4 + (tid >> 6)] = s2; }
  __syncthreads();
  s = rs[0] + rs[1] + rs[2] + rs[3];
  s2 = rs[4] + rs[5] + rs[6] + rs[7];
  const float mu = s * (1.0f / DD);
  const float var = s2 * (1.0f / DD) - mu * mu;
  const float inv = rsqrtf(var + 1e-5f);
  u16* o = out + base;
#pragma unroll
  for (int c = 0; c < 3; ++c) {
    int d = tid + c * 256;
    o[d] = f2bf((v[c] - mu) * inv * w[d] + b[d]);
  }
}

// ---------------------------------------------------------------- flash attention
// One block per (z, q-tile of 64). 4 waves, wave w owns q rows [w*16, w*16+16).
// Swapped QK^T: S^T = mfma(K_frag, Q_frag) -> lane owns one q-column; row-softmax
// = 16 in-lane values + shfl_xor(16,32) across quads. P goes through a per-wave
// padded LDS scratch (pitch 72) to reach the MFMA A-layout. K/V/Q tiles staged
// via global_load_lds with both-sides XOR swizzle chunk^=(row>>1)&7.
// K/V double-buffered; one barrier per kv-tile.
__global__ __launch_bounds__(256, 3) void flash_attn(
    const u16* __restrict__ qkv, const u16* __restrict__ vT,
    u16* __restrict__ attn) {
  __shared__ __align__(16) u16 Qs[64 * 64];
  __shared__ __align__(16) u16 Ks0[64 * 64];
  __shared__ __align__(16) u16 Ks1[64 * 64];
  __shared__ __align__(16) u16 Vs0[64 * 64];
  __shared__ __align__(16) u16 Vs1[64 * 64];
  __shared__ __align__(16) u16 Ps[4 * 16 * 72];

  const int id = blockIdx.x;            // 384 = 16 q-tiles * 24 z
  const int qt = 15 - id / 24;          // heavy q-tiles dispatched first
  const int z = id % 24;
  const int b = z / NH, h = z - (z / NH) * NH;
  const int q0 = qt * 64;

  const int tid = threadIdx.x;
  const int lane = tid & 63;
  const int wave = __builtin_amdgcn_readfirstlane(tid >> 6);
  const int mf = lane & 15;
  const int quad = lane >> 4;

  // staging: wave w fills tile rows [w*16, w*16+16), 2 issues of 1024B
  const int srow = wave * 16 + (lane >> 3);
  const int srow1 = srow + 8;
  const int sch0 = (((lane & 7) ^ ((srow >> 1) & 7))) * 8;   // swizzled col (elems)
  const int sch1 = (((lane & 7) ^ ((srow1 >> 1) & 7))) * 8;
  const int lb = wave * 1024;  // wave-uniform LDS base (elems)

  const u16* qk_base = qkv + (long long)b * TT * 2304 + h * 64;

  auto stageKV = [&](u16* Kd, u16* Vd, int kv0) {
    load_lds16(qk_base + (long long)(kv0 + srow) * 2304 + 768 + sch0, Kd + lb);
    load_lds16(qk_base + (long long)(kv0 + srow1) * 2304 + 768 + sch1, Kd + lb + 512);
    load_lds16(vT + (long long)(z * 64 + srow) * 1024 + kv0 + sch0, Vd + lb);
    load_lds16(vT + (long long)(z * 64 + srow1) * 1024 + kv0 + sch1, Vd + lb + 512);
  };

  // stage Q + first K/V
  load_lds16(qk_base + (long long)(q0 + srow) * 2304 + sch0, Qs + lb);
  load_lds16(qk_base + (long long)(q0 + srow1) * 2304 + sch1, Qs + lb + 512);
  stageKV(Ks0, Vs0, 0);
  __syncthreads();

  // Q fragments (B-operand: row q = wave*16+mf, k = ks*32+quad*8)
  bf16x8 qfr[2];
  {
    const int r = wave * 16 + mf;
    const int sw = (r >> 1) & 7;
#pragma unroll
    for (int ks = 0; ks < 2; ++ks)
      qfr[ks] = *(const bf16x8*)(Qs + r * 64 + (((ks * 4 + quad) ^ sw) * 8));
  }

  f32x4 oacc[4] = {};
  float mrun = -1e30f, lrun = 0.f;
  u16 *Kc = Ks0, *Vc = Vs0, *Kn = Ks1, *Vn = Vs1;

  for (int t = 0; t <= qt; ++t) {
    if (t < qt) stageKV(Kn, Vn, (t + 1) * 64);
    const int diag = (t == qt);

    // S^T[kv][q] = sum_d K[kv][d] * Q[q][d]
    f32x4 sacc[4] = {};
#pragma unroll
    for (int ks = 0; ks < 2; ++ks)
#pragma unroll
      for (int i = 0; i < 4; ++i) {
        const int r = i * 16 + mf;
        bf16x8 kfr = *(const bf16x8*)(Kc + r * 64 + (((ks * 4 + quad) ^ ((r >> 1) & 7)) * 8));
        sacc[i] = __builtin_amdgcn_mfma_f32_16x16x32_bf16(kfr, qfr[ks], sacc[i], 0, 0, 0);
      }

    // online softmax over this tile (lane owns q = wave*16+mf; kv = i*16+quad*4+r)
    float pv[4][4];
    float tmax = -1e30f;
#pragma unroll
    for (int i = 0; i < 4; ++i)
#pragma unroll
      for (int r = 0; r < 4; ++r) {
        float v = sacc[i][r] * 0.125f;
        if (diag) {
          const int kvl = i * 16 + quad * 4 + r;
          if (kvl > wave * 16 + mf) v = -1e30f;
        }
        pv[i][r] = v;
        tmax = fmaxf(tmax, v);
      }
    tmax = fmaxf(tmax, __shfl_xor(tmax, 16, 64));
    tmax = fmaxf(tmax, __shfl_xor(tmax, 32, 64));
    const float mnew = fmaxf(mrun, tmax);
    const float fac = __expf(mrun - mnew);  // first tile: exp(-huge) = 0
    float lsum = 0.f;
#pragma unroll
    for (int i = 0; i < 4; ++i)
#pragma unroll
      for (int r = 0; r < 4; ++r) {
        float e = __expf(pv[i][r] - mnew);
        pv[i][r] = e;
        lsum += e;
      }
    lsum += __shfl_xor(lsum, 16, 64);
    lsum += __shfl_xor(lsum, 32, 64);
    lrun = lrun * fac + lsum;
    mrun = mnew;

    // rescale O: factor for q-row (quad*4+r) lives at lane (same quad, mf=quad*4+r)
    float fo[4];
#pragma unroll
    for (int r = 0; r < 4; ++r) fo[r] = __shfl(fac, (lane & 48) | (quad * 4 + r), 64);
#pragma unroll
    for (int j = 0; j < 4; ++j)
#pragma unroll
      for (int r = 0; r < 4; ++r) oacc[j][r] *= fo[r];

    // P -> per-wave LDS scratch [16 q][72 pitch] (bf16)
#pragma unroll
    for (int i = 0; i < 4; ++i) {
      u16x4 pk;
#pragma unroll
      for (int r = 0; r < 4; ++r) pk[r] = f2bf(pv[i][r]);
      *(u16x4*)(Ps + wave * 1152 + mf * 72 + i * 16 + quad * 4) = pk;
    }
    // PV: O[q][d] += sum_kv P[q][kv] * V^T[d][kv]
#pragma unroll
    for (int ks = 0; ks < 2; ++ks) {
      bf16x8 pfr = *(const bf16x8*)(Ps + wave * 1152 + mf * 72 + ks * 32 + quad * 8);
#pragma unroll
      for (int j = 0; j < 4; ++j) {
        const int r = j * 16 + mf;
        bf16x8 vfr = *(const bf16x8*)(Vc + r * 64 + (((ks * 4 + quad) ^ ((r >> 1) & 7)) * 8));
        oacc[j] = __builtin_amdgcn_mfma_f32_16x16x32_bf16(pfr, vfr, oacc[j], 0, 0, 0);
      }
    }
    __syncthreads();  // all waves done with cur bufs; next bufs' loads drained
    u16* tk = Kc; Kc = Kn; Kn = tk;
    u16* tv = Vc; Vc = Vn; Vn = tv;
  }

  // epilogue: O / l ; output lane holds d = j*16+mf, q = wave*16 + quad*4 + r
  const float linv = 1.0f / lrun;
  float li[4];
#pragma unroll
  for (int r = 0; r < 4; ++r) li[r] = __shfl(linv, (lane & 48) | (quad * 4 + r), 64);
#pragma unroll
  for (int j = 0; j < 4; ++j)
#pragma unroll
    for (int r = 0; r < 4; ++r) {
      const int q = q0 + wave * 16 + quad * 4 + r;
      const int d = j * 16 + mf;
      attn[(long long)(b * TT + q) * 768 + h * 64 + d] = f2bf(oacc[j][r] * li[r]);
    }
}

// ---------------------------------------------------------------- GEMM (NT)
// C[z][m][n] = sum_k A[z][m][k] * B[z][n][k]  (+ epilogue)
// 128x128 tile, BK=32, 2-phase double-buffered pipeline, 3 blocks/CU.
// (R5+R8 lesson: at 2-phase, blocks/CU > tile size — 256-wide tiles at 1-2
// blocks/CU regress; the barrier drain stalls the whole CU.)
// Staging via global_load_lds dwordx4 (linear LDS dest). Bank-conflict fix
// (rule 21): 16B-chunk XOR swizzle chunk^=(row>>1)&3 on global source AND
// ds_read addresses. xcdChunk: bijective chunked XCD swizzle (T1).
// kSplit>1: blockIdx.z = K-slice; EPI_SPLITK_PART writes plain partials to
// Cout + z*M*ldc (bias folded into slice 0); the next ln_sum folds them.
// R6 lesson: NO nontemporal stores on fragment epilogues (1.75x regression).
// R9: f32 outputs (EPI_F32 / EPI_SPLITK_PART) go through a per-wave LDS
// transpose so each store instruction writes 256B contiguous per row —
// fixes the 1.55x write amplification of 64B fragment stores.
enum { EPI_F32 = 0, EPI_BF16_BIAS = 1, EPI_BF16_BIAS_GELU = 2,
       EPI_BF16 = 4, EPI_QKV = 5, EPI_SPLITK_PART = 6 };

template <int EPI>
__global__ __launch_bounds__(256, 3) void gemm_nt(
    const u16* __restrict__ A, const u16* __restrict__ Bm,
    const float* __restrict__ bias,
    void* __restrict__ Cout, u16* __restrict__ vtAux,
    int M, int N, int K, int lda, int ldb, int ldc,
    long long aHi, long long aLo, long long bHi, long long bLo,
    long long cHi, long long cLo, int Hdiv, int swapxy,
    int xcdChunk, int kSplit) {
  __shared__ __align__(16) u16 SMEM[4 * 128 * 32];  // As0|As1|Bs0|Bs1 (32 KB)
  u16* const As0 = SMEM;
  u16* const As1 = SMEM + 4096;
  u16* const Bs0 = SMEM + 8192;
  u16* const Bs1 = SMEM + 12288;
  const int z = blockIdx.z;
  int zb = 0, zh = 0;
  long long koff = 0;
  if (kSplit > 1) {          // z = K-slice index (batch/head decomposition off)
    const int slice = K / kSplit;
    koff = (long long)z * slice;
    K = slice;
  } else {
    zb = z / Hdiv; zh = z - zb * Hdiv;
  }
  const u16* Ab = A + zb * aHi + zh * aLo + koff;
  const u16* Bb = Bm + zb * bHi + zh * bLo + koff;
  const long long cOff = (long long)zb * cHi + (long long)zh * cLo;

  int rx = blockIdx.x, ry = blockIdx.y;
  if (xcdChunk) {  // per-XCD contiguous work chunks (bijective: nwg%8==0)
    const int id = ry * gridDim.x + rx;
    const int w = (id & 7) * xcdChunk + (id >> 3);
    rx = w % gridDim.x;
    ry = w / gridDim.x;
  }
  const int bx = swapxy ? ry : rx;  // swapxy=1: M fastest for B-panel reuse
  const int by = swapxy ? rx : ry;
  const int m0 = by * 128;
  const int n0 = bx * 128;

  const int tid = threadIdx.x;
  const int lane = tid & 63;
  const int wave = __builtin_amdgcn_readfirstlane(tid >> 6);
  const int wm = (wave >> 1) * 64;
  const int wn = (wave & 1) * 64;
  const int mf = lane & 15;
  const int quad = lane >> 4;

  // ---- staging geometry: wave w fills tile rows [w*32, w*32+32)
  const int sr0 = wave * 32 + (lane >> 2);
  const int sr1 = sr0 + 16;
  const int sc0 = ((lane & 3) ^ ((sr0 >> 1) & 3)) * 8;  // swizzled source col
  const int sc1 = ((lane & 3) ^ ((sr1 >> 1) & 3)) * 8;
  int br0 = n0 + sr0; if (br0 >= N) br0 = N - 1;
  int br1 = n0 + sr1; if (br1 >= N) br1 = N - 1;
  const u16* agp0 = Ab + (long long)(m0 + sr0) * lda + sc0;  // M always %128==0
  const u16* agp1 = Ab + (long long)(m0 + sr1) * lda + sc1;
  const u16* bgp0 = Bb + (long long)br0 * ldb + sc0;
  const u16* bgp1 = Bb + (long long)br1 * ldb + sc1;
  const int woff = wave * 1024;

  auto stage = [&](u16* Ad, u16* Bd, int kk) {
    load_lds16(agp0 + kk, Ad + woff);
    load_lds16(agp1 + kk, Ad + woff + 512);
    load_lds16(bgp0 + kk, Bd + woff);
    load_lds16(bgp1 + kk, Bd + woff + 512);
  };

  // ---- fragment read offsets (swizzled, constant over K-loop)
  int aoff[4], boff[4];
#pragma unroll
  for (int i = 0; i < 4; ++i) {
    const int ar = wm + i * 16 + mf;
    aoff[i] = ar * 32 + ((quad ^ ((ar >> 1) & 3)) * 8);
    const int br = wn + i * 16 + mf;
    boff[i] = br * 32 + ((quad ^ ((br >> 1) & 3)) * 8);
  }

  f32x4 acc[4][4] = {};

  auto compute = [&](const u16* Asb, const u16* Bsb) {
    bf16x8 afr[4], bfr[4];
#pragma unroll
    for (int i = 0; i < 4; ++i) afr[i] = *(const bf16x8*)(Asb + aoff[i]);
#pragma unroll
    for (int j = 0; j < 4; ++j) bfr[j] = *(const bf16x8*)(Bsb + boff[j]);
#pragma unroll
    for (int i = 0; i < 4; ++i)
#pragma unroll
      for (int j = 0; j < 4; ++j)
        acc[i][j] = __builtin_amdgcn_mfma_f32_16x16x32_bf16(afr[i], bfr[j], acc[i][j], 0, 0, 0);
  };

  // 2-phase pipeline, unrolled x2 (all K here have an even number of 32-steps)
  stage(As0, Bs0, 0);
  __syncthreads();
  for (int k0 = 0; k0 < K; k0 += 64) {
    if (k0 + 32 < K) stage(As1, Bs1, k0 + 32);
    compute(As0, Bs0);
    __syncthreads();
    if (k0 + 64 < K) stage(As0, Bs0, k0 + 64);
    compute(As1, Bs1);
    __syncthreads();
  }
  // after the final barrier the staging LDS is dead — reusable as epilogue scratch

  if (EPI == EPI_F32 || EPI == EPI_SPLITK_PART) {
    // coalesced f32 epilogue: per-wave 8 KB LDS transpose (wave-private,
    // no barriers). Each store instruction then writes 256B contiguous.
    float* scr = (float*)SMEM + wave * 2048;  // 32 rows x 64 cols f32
    float* outB = (EPI == EPI_SPLITK_PART)
        ? ((float*)Cout + (long long)z * M * ldc)
        : ((float*)Cout + cOff);
#pragma unroll
    for (int h = 0; h < 2; ++h) {
#pragma unroll
      for (int ii = 0; ii < 2; ++ii)
#pragma unroll
        for (int j = 0; j < 4; ++j) {
          const int lc = j * 16 + mf;
          float bv = 0.0f;
          if (EPI == EPI_SPLITK_PART && z == 0) bv = bias[n0 + wn + lc];
#pragma unroll
          for (int r = 0; r < 4; ++r)
            scr[(ii * 16 + quad * 4 + r) * 64 + lc] = acc[2 * h + ii][j][r] + bv;
        }
      const long long row0 = m0 + wm + h * 32;
      const int gcol = n0 + wn + lane;
      if (gcol < N) {
#pragma unroll
        for (int t = 0; t < 32; ++t)
          outB[(row0 + t) * ldc + gcol] = scr[t * 64 + lane];
      }
    }
    return;
  }

#pragma unroll
  for (int j = 0; j < 4; ++j) {
    const int col = n0 + wn + j * 16 + mf;
    if (col >= N) continue;
    float bv = 0.0f;
    if (EPI == EPI_BF16_BIAS || EPI == EPI_BF16_BIAS_GELU || EPI == EPI_QKV)
      bv = bias[col];
    if (EPI == EPI_QKV && col >= 1536) {
      // V columns: write transposed into vT[(b*NH+h)*64+d][t], packed x4
      const int hd = col - 1536;
#pragma unroll
      for (int i = 0; i < 4; ++i) {
        const int t0 = m0 + wm + i * 16 + quad * 4;  // 4 consecutive t
        u16x4 pk;
#pragma unroll
        for (int r = 0; r < 4; ++r) pk[r] = f2bf(acc[i][j][r] + bv);
        const int b_ = t0 >> 10;
        const long long vi =
            ((long long)((b_ * NH + (hd >> 6)) * 64 + (hd & 63))) * 1024 + (t0 & 1023);
        *(u16x4*)(vtAux + vi) = pk;
      }
      continue;
    }
#pragma unroll
    for (int i = 0; i < 4; ++i) {
#pragma unroll
      for (int r = 0; r < 4; ++r) {
        const int row = m0 + wm + i * 16 + quad * 4 + r;
        float v = acc[i][j][r] + bv;
        if (EPI == EPI_BF16_BIAS_GELU) {
          float u = v + 0.044715f * v * v * v;
          v = 0.5f * v * (1.0f + tanhf(0.7978845608028654f * u));
        }
        const long long ci = cOff + (long long)row * ldc + col;
        ((u16*)Cout)[ci] = f2bf(v);
      }
    }
  }
}

// ---------------------------------------------------------------- launch
extern "C" void kernel_launch(void* const* d_in, const int* in_sizes, int n_in,
                              void* d_out, int out_size, void* d_ws, size_t ws_size,
                              hipStream_t stream) {
  const int* tokens      = (const int*)d_in[0];
  const float* tok_embed = (const float*)d_in[1];
  const float* pos_embed = (const float*)d_in[2];
  const float* qkv_w     = (const float*)d_in[3];
  const float* qkv_b     = (const float*)d_in[4];
  const float* proj_w    = (const float*)d_in[5];
  const float* proj_b    = (const float*)d_in[6];
  const float* ln1_w     = (const float*)d_in[7];
  const float* ln1_b     = (const float*)d_in[8];
  const float* ln2_w     = (const float*)d_in[9];
  const float* ln2_b     = (const float*)d_in[10];
  const float* fc1_w     = (const float*)d_in[11];
  const float* fc1_b     = (const float*)d_in[12];
  const float* fc2_w     = (const float*)d_in[13];
  const float* fc2_b     = (const float*)d_in[14];
  const float* lnf_w     = (const float*)d_in[15];
  const float* lnf_b     = (const float*)d_in[16];

  if (ws_size < 440u * 1024u * 1024u) return;  // scratch guard

  char* p = (char*)d_ws;
  auto alloc = [&](size_t bytes) {
    void* r = (void*)p;
    p += (bytes + 255) & ~(size_t)255;
    return r;
  };
  u16* wq   = (u16*)alloc((size_t)NL * 2304 * 768 * 2);  // qkv_w^T  [L][2304][768]
  u16* wp   = (u16*)alloc((size_t)NL * 768 * 768 * 2);   // proj_w^T [L][768][768]
  u16* w1   = (u16*)alloc((size_t)NL * 3072 * 768 * 2);  // fc1_w^T  [L][3072][768]
  u16* w2   = (u16*)alloc((size_t)NL * 768 * 3072 * 2);  // fc2_w^T  [L][768][3072]
  u16* te   = (u16*)alloc((size_t)VOC * 768 * 2);        // tok_embed bf16 [V][768]
  float* x  = (float*)alloc((size_t)BT * 768 * 4);       // residual stream fp32
  u16* hbuf = (u16*)alloc((size_t)BT * 768 * 2);         // LN output bf16
  u16* qkv  = (u16*)alloc((size_t)BT * 2304 * 2);
  u16* vT   = (u16*)alloc((size_t)24 * 64 * 1024 * 2);   // [b,h][64][1024]
  u16* attn = (u16*)alloc((size_t)BT * 768 * 2);
  u16* ff   = (u16*)alloc((size_t)BT * 3072 * 2);
  u16* xf   = (u16*)alloc((size_t)BT * 768 * 2);
  float* pp = (float*)alloc((size_t)4 * BT * 768 * 4);   // split-K partials

  // weight conversion (per call; ws is re-poisoned before every timed launch)
  transpose_convert<<<dim3(2304 / 32, 768 / 32, NL), 256, 0, stream>>>(qkv_w, wq, 768, 2304);
  transpose_convert<<<dim3(768 / 32, 768 / 32, NL), 256, 0, stream>>>(proj_w, wp, 768, 768);
  transpose_convert<<<dim3(3072 / 32, 768 / 32, NL), 256, 0, stream>>>(fc1_w, w1, 768, 3072);
  transpose_convert<<<dim3(768 / 32, 3072 / 32, NL), 256, 0, stream>>>(fc2_w, w2, 3072, 768);
  convert_bf16<<<4096, 256, 0, stream>>>(tok_embed, te, (long long)VOC * 768);
  embed_kernel<<<BT, 256, 0, stream>>>(tokens, tok_embed, pos_embed, x);

  for (int l = 0; l < NL; ++l) {
    // ln1: fold previous layer's fc2 partials (4 slices) into x, then LN
    ln_sum<<<BT, 256, 0, stream>>>(x, pp, l == 0 ? 0 : 4,
                                   ln1_w + l * 768, ln1_b + l * 768, hbuf);
    // qkv GEMM; V columns (>=1536) go transposed straight into vT
    gemm_nt<EPI_QKV><<<dim3(2304 / 128, BT / 128, 1), 256, 0, stream>>>(
        hbuf, wq + (size_t)l * 2304 * 768, qkv_b + l * 2304, qkv, vT,
        BT, 2304, 768, 768, 768, 2304, 0, 0, 0, 0, 0, 0, 1, 0, 288 / 8, 1);
    // fused flash attention: QK^T + causal online-softmax + PV in one pass
    flash_attn<<<384, 256, 0, stream>>>(qkv, vT, attn);
    // proj: split-K x3 (288 blocks, full-chip), coalesced partial writes
    gemm_nt<EPI_SPLITK_PART><<<dim3(768 / 128, BT / 128, 3), 256, 0, stream>>>(
        attn, wp + (size_t)l * 768 * 768, proj_b + l * 768, pp, nullptr,
        BT, 768, 768, 768, 768, 768, 0, 0, 0, 0, 0, 0, 1, 0, 96 / 8, 3);
    // ln2: x += proj partials (3 slices), then LN
    ln_sum<<<BT, 256, 0, stream>>>(x, pp, 3,
                                   ln2_w + l * 768, ln2_b + l * 768, hbuf);
    gemm_nt<EPI_BF16_BIAS_GELU><<<dim3(3072 / 128, BT / 128, 1), 256, 0, stream>>>(
        hbuf, w1 + (size_t)l * 3072 * 768, fc1_b + l * 3072, ff, nullptr,
        BT, 3072, 768, 768, 768, 3072, 0, 0, 0, 0, 0, 0, 1, 0, 384 / 8, 1);
    // fc2: split-K x4 (384 blocks), coalesced partial writes
    gemm_nt<EPI_SPLITK_PART><<<dim3(768 / 128, BT / 128, 4), 256, 0, stream>>>(
        ff, w2 + (size_t)l * 768 * 3072, fc2_b + l * 768, pp, nullptr,
        BT, 768, 3072, 3072, 3072, 768, 0, 0, 0, 0, 0, 0, 1, 0, 96 / 8, 4);
  }
  // final LN folds the last fc2 partials
  ln_sum<<<BT, 256, 0, stream>>>(x, pp, 4, lnf_w, lnf_b, xf);
  // lm_head: 128x128 tile (16x393 grid), M fastest + chunked XCD swizzle,
  // coalesced LDS-transposed epilogue (6288 % 8 == 0)
  gemm_nt<EPI_F32><<<dim3(BT / 128, (VOC + 127) / 128, 1), 256, 0, stream>>>(
      xf, te, nullptr, (float*)d_out, nullptr,
      BT, VOC, 768, 768, 768, VOC, 0, 0, 0, 0, 0, 0, 1, 1, 6288 / 8, 1);
}

// Round 10
// 2379.372 us; speedup vs baseline: 1.0942x; 1.0216x over previous
//
#include <hip/hip_runtime.h>

#define TT 1024
#define DD 768
#define FFD 3072
#define NH 12
#define NL 12
#define HDIM 64
#define VOC 50257
#define BT 2048  // B*T

typedef __attribute__((ext_vector_type(8))) __bf16 bf16x8;
typedef __attribute__((ext_vector_type(4))) float f32x4;
typedef __attribute__((ext_vector_type(4))) unsigned short u16x4;
typedef unsigned short u16;

static __device__ __forceinline__ u16 f2bf(float f) {
  unsigned int u = __float_as_uint(f);
  u += 0x7FFF + ((u >> 16) & 1);  // round-to-nearest-even
  return (u16)(u >> 16);
}

// async global->LDS, 16B per lane; LDS dest = wave-uniform base + lane*16
static __device__ __forceinline__ void load_lds16(const u16* g, u16* l) {
  __builtin_amdgcn_global_load_lds(
      (const __attribute__((address_space(1))) unsigned int*)g,
      (__attribute__((address_space(3))) unsigned int*)l, 16, 0, 0);
}

// ---------------------------------------------------------------- converts
__global__ __launch_bounds__(256) void transpose_convert(
    const float* __restrict__ in, u16* __restrict__ out, int R, int C) {
  __shared__ float tile[32][33];
  const long long zo = (long long)blockIdx.z * R * C;
  const int c0 = blockIdx.x * 32, r0 = blockIdx.y * 32;
  const int tx = threadIdx.x & 31, ty = threadIdx.x >> 5;
#pragma unroll
  for (int i = 0; i < 32; i += 8)
    tile[ty + i][tx] = in[zo + (long long)(r0 + ty + i) * C + c0 + tx];
  __syncthreads();
#pragma unroll
  for (int i = 0; i < 32; i += 8)
    out[zo + (long long)(c0 + ty + i) * R + r0 + tx] = f2bf(tile[tx][ty + i]);
}

__global__ void convert_bf16(const float* __restrict__ in, u16* __restrict__ out,
                             long long n) {
  long long i = (long long)blockIdx.x * 256 + threadIdx.x;
  const long long stride = (long long)gridDim.x * 256;
  for (; i < n; i += stride) out[i] = f2bf(in[i]);
}

// ---------------------------------------------------------------- embed
__global__ __launch_bounds__(256) void embed_kernel(
    const int* __restrict__ tokens, const float* __restrict__ tokE,
    const float* __restrict__ posE, float* __restrict__ x) {
  const int row = blockIdx.x;        // b*1024 + t
  const int t = row & (TT - 1);
  const int tok = tokens[row];
  const int tid = threadIdx.x;
#pragma unroll
  for (int c = 0; c < 3; ++c) {
    int d = tid + c * 256;
    x[(long long)row * DD + d] = tokE[(long long)tok * DD + d] + posE[(long long)t * DD + d];
  }
}

// ---------------------------------------------------------------- layernorm (+ split-K partial fold)
// nsum>0: x[row] += sum of nsum partial slices (pp), written back to x, then LN.
// float4 I/O (16B/lane, G13); threads 0..191 carry data, wave 3 idles on loads.
__global__ __launch_bounds__(256) void ln_sum(
    float* __restrict__ x, const float* __restrict__ pp, int nsum,
    const float* __restrict__ w, const float* __restrict__ b,
    u16* __restrict__ out) {
  const int row = blockIdx.x;
  const long long base = (long long)row * DD;
  const int tid = threadIdx.x;
  f32x4 v = {0.f, 0.f, 0.f, 0.f};
  float s = 0.f, s2 = 0.f;
  if (tid < 192) {
    v = *(const f32x4*)(x + base + tid * 4);
    for (int q = 0; q < nsum; ++q) {
      f32x4 pv = *(const f32x4*)(pp + (long long)q * BT * DD + base + tid * 4);
#pragma unroll
      for (int c = 0; c < 4; ++c) v[c] += pv[c];
    }
    if (nsum) *(f32x4*)(x + base + tid * 4) = v;
#pragma unroll
    for (int c = 0; c < 4; ++c) { s += v[c]; s2 += v[c] * v[c]; }
  }
  for (int off = 32; off; off >>= 1) {
    s += __shfl_down(s, off, 64);
    s2 += __shfl_down(s2, off, 64);
  }
  __shared__ float rs[8];
  if ((tid & 63) == 0) { rs[tid >> 6] = s; rs[4 + (tid >> 6)] = s2; }
  __syncthreads();
  s = rs[0] + rs[1] + rs[2] + rs[3];
  s2 = rs[4] + rs[5] + rs[6] + rs[7];
  const float mu = s * (1.0f / DD);
  const float var = s2 * (1.0f / DD) - mu * mu;
  const float inv = rsqrtf(var + 1e-5f);
  if (tid < 192) {
    f32x4 wv = *(const f32x4*)(w + tid * 4);
    f32x4 bv = *(const f32x4*)(b + tid * 4);
    u16x4 o;
#pragma unroll
    for (int c = 0; c < 4; ++c) o[c] = f2bf((v[c] - mu) * inv * wv[c] + bv[c]);
    *(u16x4*)(out + base + tid * 4) = o;
  }
}

// ---------------------------------------------------------------- flash attention
// One block per (z, q-tile of 64). 4 waves, wave w owns q rows [w*16, w*16+16).
// Swapped QK^T: S^T = mfma(K_frag, Q_frag) -> lane owns one q-column; row-softmax
// = 16 in-lane values + shfl_xor(16,32) across quads. P goes through a per-wave
// padded LDS scratch (pitch 72) to reach the MFMA A-layout. K/V/Q tiles staged
// via global_load_lds with both-sides XOR swizzle chunk^=(row>>1)&7.
// K/V double-buffered; one barrier per kv-tile.
__global__ __launch_bounds__(256, 3) void flash_attn(
    const u16* __restrict__ qkv, const u16* __restrict__ vT,
    u16* __restrict__ attn) {
  __shared__ __align__(16) u16 Qs[64 * 64];
  __shared__ __align__(16) u16 Ks0[64 * 64];
  __shared__ __align__(16) u16 Ks1[64 * 64];
  __shared__ __align__(16) u16 Vs0[64 * 64];
  __shared__ __align__(16) u16 Vs1[64 * 64];
  __shared__ __align__(16) u16 Ps[4 * 16 * 72];

  const int id = blockIdx.x;            // 384 = 16 q-tiles * 24 z
  const int qt = 15 - id / 24;          // heavy q-tiles dispatched first
  const int z = id % 24;
  const int b = z / NH, h = z - (z / NH) * NH;
  const int q0 = qt * 64;

  const int tid = threadIdx.x;
  const int lane = tid & 63;
  const int wave = __builtin_amdgcn_readfirstlane(tid >> 6);
  const int mf = lane & 15;
  const int quad = lane >> 4;

  // staging: wave w fills tile rows [w*16, w*16+16), 2 issues of 1024B
  const int srow = wave * 16 + (lane >> 3);
  const int srow1 = srow + 8;
  const int sch0 = (((lane & 7) ^ ((srow >> 1) & 7))) * 8;   // swizzled col (elems)
  const int sch1 = (((lane & 7) ^ ((srow1 >> 1) & 7))) * 8;
  const int lb = wave * 1024;  // wave-uniform LDS base (elems)

  const u16* qk_base = qkv + (long long)b * TT * 2304 + h * 64;

  auto stageKV = [&](u16* Kd, u16* Vd, int kv0) {
    load_lds16(qk_base + (long long)(kv0 + srow) * 2304 + 768 + sch0, Kd + lb);
    load_lds16(qk_base + (long long)(kv0 + srow1) * 2304 + 768 + sch1, Kd + lb + 512);
    load_lds16(vT + (long long)(z * 64 + srow) * 1024 + kv0 + sch0, Vd + lb);
    load_lds16(vT + (long long)(z * 64 + srow1) * 1024 + kv0 + sch1, Vd + lb + 512);
  };

  // stage Q + first K/V
  load_lds16(qk_base + (long long)(q0 + srow) * 2304 + sch0, Qs + lb);
  load_lds16(qk_base + (long long)(q0 + srow1) * 2304 + sch1, Qs + lb + 512);
  stageKV(Ks0, Vs0, 0);
  __syncthreads();

  // Q fragments (B-operand: row q = wave*16+mf, k = ks*32+quad*8)
  bf16x8 qfr[2];
  {
    const int r = wave * 16 + mf;
    const int sw = (r >> 1) & 7;
#pragma unroll
    for (int ks = 0; ks < 2; ++ks)
      qfr[ks] = *(const bf16x8*)(Qs + r * 64 + (((ks * 4 + quad) ^ sw) * 8));
  }

  f32x4 oacc[4] = {};
  float mrun = -1e30f, lrun = 0.f;
  u16 *Kc = Ks0, *Vc = Vs0, *Kn = Ks1, *Vn = Vs1;

  for (int t = 0; t <= qt; ++t) {
    if (t < qt) stageKV(Kn, Vn, (t + 1) * 64);
    const int diag = (t == qt);

    // S^T[kv][q] = sum_d K[kv][d] * Q[q][d]
    f32x4 sacc[4] = {};
#pragma unroll
    for (int ks = 0; ks < 2; ++ks)
#pragma unroll
      for (int i = 0; i < 4; ++i) {
        const int r = i * 16 + mf;
        bf16x8 kfr = *(const bf16x8*)(Kc + r * 64 + (((ks * 4 + quad) ^ ((r >> 1) & 7)) * 8));
        sacc[i] = __builtin_amdgcn_mfma_f32_16x16x32_bf16(kfr, qfr[ks], sacc[i], 0, 0, 0);
      }

    // online softmax over this tile (lane owns q = wave*16+mf; kv = i*16+quad*4+r)
    float pv[4][4];
    float tmax = -1e30f;
#pragma unroll
    for (int i = 0; i < 4; ++i)
#pragma unroll
      for (int r = 0; r < 4; ++r) {
        float v = sacc[i][r] * 0.125f;
        if (diag) {
          const int kvl = i * 16 + quad * 4 + r;
          if (kvl > wave * 16 + mf) v = -1e30f;
        }
        pv[i][r] = v;
        tmax = fmaxf(tmax, v);
      }
    tmax = fmaxf(tmax, __shfl_xor(tmax, 16, 64));
    tmax = fmaxf(tmax, __shfl_xor(tmax, 32, 64));
    const float mnew = fmaxf(mrun, tmax);
    const float fac = __expf(mrun - mnew);  // first tile: exp(-huge) = 0
    float lsum = 0.f;
#pragma unroll
    for (int i = 0; i < 4; ++i)
#pragma unroll
      for (int r = 0; r < 4; ++r) {
        float e = __expf(pv[i][r] - mnew);
        pv[i][r] = e;
        lsum += e;
      }
    lsum += __shfl_xor(lsum, 16, 64);
    lsum += __shfl_xor(lsum, 32, 64);
    lrun = lrun * fac + lsum;
    mrun = mnew;

    // rescale O: factor for q-row (quad*4+r) lives at lane (same quad, mf=quad*4+r)
    float fo[4];
#pragma unroll
    for (int r = 0; r < 4; ++r) fo[r] = __shfl(fac, (lane & 48) | (quad * 4 + r), 64);
#pragma unroll
    for (int j = 0; j < 4; ++j)
#pragma unroll
      for (int r = 0; r < 4; ++r) oacc[j][r] *= fo[r];

    // P -> per-wave LDS scratch [16 q][72 pitch] (bf16)
#pragma unroll
    for (int i = 0; i < 4; ++i) {
      u16x4 pk;
#pragma unroll
      for (int r = 0; r < 4; ++r) pk[r] = f2bf(pv[i][r]);
      *(u16x4*)(Ps + wave * 1152 + mf * 72 + i * 16 + quad * 4) = pk;
    }
    // PV: O[q][d] += sum_kv P[q][kv] * V^T[d][kv]
#pragma unroll
    for (int ks = 0; ks < 2; ++ks) {
      bf16x8 pfr = *(const bf16x8*)(Ps + wave * 1152 + mf * 72 + ks * 32 + quad * 8);
#pragma unroll
      for (int j = 0; j < 4; ++j) {
        const int r = j * 16 + mf;
        bf16x8 vfr = *(const bf16x8*)(Vc + r * 64 + (((ks * 4 + quad) ^ ((r >> 1) & 7)) * 8));
        oacc[j] = __builtin_amdgcn_mfma_f32_16x16x32_bf16(pfr, vfr, oacc[j], 0, 0, 0);
      }
    }
    __syncthreads();  // all waves done with cur bufs; next bufs' loads drained
    u16* tk = Kc; Kc = Kn; Kn = tk;
    u16* tv = Vc; Vc = Vn; Vn = tv;
  }

  // epilogue: O / l ; output lane holds d = j*16+mf, q = wave*16 + quad*4 + r
  const float linv = 1.0f / lrun;
  float li[4];
#pragma unroll
  for (int r = 0; r < 4; ++r) li[r] = __shfl(linv, (lane & 48) | (quad * 4 + r), 64);
#pragma unroll
  for (int j = 0; j < 4; ++j)
#pragma unroll
    for (int r = 0; r < 4; ++r) {
      const int q = q0 + wave * 16 + quad * 4 + r;
      const int d = j * 16 + mf;
      attn[(long long)(b * TT + q) * 768 + h * 64 + d] = f2bf(oacc[j][r] * li[r]);
    }
}

// ---------------------------------------------------------------- GEMM (NT)
// C[z][m][n] = sum_k A[z][m][k] * B[z][n][k]  (+ epilogue)
// 128x128 tile, BK=32, 2-phase double-buffered pipeline, 3 blocks/CU.
// (R5+R8 lesson: at 2-phase, blocks/CU > tile size — 256-wide tiles at 1-2
// blocks/CU regress; the barrier drain stalls the whole CU.)
// Staging via global_load_lds dwordx4 (linear LDS dest). Bank-conflict fix
// (rule 21): 16B-chunk XOR swizzle chunk^=(row>>1)&3 on global source AND
// ds_read addresses. xcdChunk: bijective chunked XCD swizzle (T1).
// kSplit>1: blockIdx.z = K-slice; EPI_SPLITK_PART writes plain partials to
// Cout + z*M*ldc (bias folded into slice 0); the next ln_sum folds them.
// R6 lesson: NO nontemporal stores on fragment epilogues (1.75x regression).
// R9: f32 outputs go through a per-wave LDS transpose -> 256B-contiguous
// stores (WRITE_SIZE 638->428 MB confirmed). R10: scratch column XOR'd with
// quad<<4 -> LDS write 2-way (free) instead of 4-way; read stays permutation.
enum { EPI_F32 = 0, EPI_BF16_BIAS = 1, EPI_BF16_BIAS_GELU = 2,
       EPI_BF16 = 4, EPI_QKV = 5, EPI_SPLITK_PART = 6 };

template <int EPI>
__global__ __launch_bounds__(256, 3) void gemm_nt(
    const u16* __restrict__ A, const u16* __restrict__ Bm,
    const float* __restrict__ bias,
    void* __restrict__ Cout, u16* __restrict__ vtAux,
    int M, int N, int K, int lda, int ldb, int ldc,
    long long aHi, long long aLo, long long bHi, long long bLo,
    long long cHi, long long cLo, int Hdiv, int swapxy,
    int xcdChunk, int kSplit) {
  __shared__ __align__(16) u16 SMEM[4 * 128 * 32];  // As0|As1|Bs0|Bs1 (32 KB)
  u16* const As0 = SMEM;
  u16* const As1 = SMEM + 4096;
  u16* const Bs0 = SMEM + 8192;
  u16* const Bs1 = SMEM + 12288;
  const int z = blockIdx.z;
  int zb = 0, zh = 0;
  long long koff = 0;
  if (kSplit > 1) {          // z = K-slice index (batch/head decomposition off)
    const int slice = K / kSplit;
    koff = (long long)z * slice;
    K = slice;
  } else {
    zb = z / Hdiv; zh = z - zb * Hdiv;
  }
  const u16* Ab = A + zb * aHi + zh * aLo + koff;
  const u16* Bb = Bm + zb * bHi + zh * bLo + koff;
  const long long cOff = (long long)zb * cHi + (long long)zh * cLo;

  int rx = blockIdx.x, ry = blockIdx.y;
  if (xcdChunk) {  // per-XCD contiguous work chunks (bijective: nwg%8==0)
    const int id = ry * gridDim.x + rx;
    const int w = (id & 7) * xcdChunk + (id >> 3);
    rx = w % gridDim.x;
    ry = w / gridDim.x;
  }
  const int bx = swapxy ? ry : rx;  // swapxy=1: M fastest for B-panel reuse
  const int by = swapxy ? rx : ry;
  const int m0 = by * 128;
  const int n0 = bx * 128;

  const int tid = threadIdx.x;
  const int lane = tid & 63;
  const int wave = __builtin_amdgcn_readfirstlane(tid >> 6);
  const int wm = (wave >> 1) * 64;
  const int wn = (wave & 1) * 64;
  const int mf = lane & 15;
  const int quad = lane >> 4;

  // ---- staging geometry: wave w fills tile rows [w*32, w*32+32)
  const int sr0 = wave * 32 + (lane >> 2);
  const int sr1 = sr0 + 16;
  const int sc0 = ((lane & 3) ^ ((sr0 >> 1) & 3)) * 8;  // swizzled source col
  const int sc1 = ((lane & 3) ^ ((sr1 >> 1) & 3)) * 8;
  int br0 = n0 + sr0; if (br0 >= N) br0 = N - 1;
  int br1 = n0 + sr1; if (br1 >= N) br1 = N - 1;
  const u16* agp0 = Ab + (long long)(m0 + sr0) * lda + sc0;  // M always %128==0
  const u16* agp1 = Ab + (long long)(m0 + sr1) * lda + sc1;
  const u16* bgp0 = Bb + (long long)br0 * ldb + sc0;
  const u16* bgp1 = Bb + (long long)br1 * ldb + sc1;
  const int woff = wave * 1024;

  auto stage = [&](u16* Ad, u16* Bd, int kk) {
    load_lds16(agp0 + kk, Ad + woff);
    load_lds16(agp1 + kk, Ad + woff + 512);
    load_lds16(bgp0 + kk, Bd + woff);
    load_lds16(bgp1 + kk, Bd + woff + 512);
  };

  // ---- fragment read offsets (swizzled, constant over K-loop)
  int aoff[4], boff[4];
#pragma unroll
  for (int i = 0; i < 4; ++i) {
    const int ar = wm + i * 16 + mf;
    aoff[i] = ar * 32 + ((quad ^ ((ar >> 1) & 3)) * 8);
    const int br = wn + i * 16 + mf;
    boff[i] = br * 32 + ((quad ^ ((br >> 1) & 3)) * 8);
  }

  f32x4 acc[4][4] = {};

  auto compute = [&](const u16* Asb, const u16* Bsb) {
    bf16x8 afr[4], bfr[4];
#pragma unroll
    for (int i = 0; i < 4; ++i) afr[i] = *(const bf16x8*)(Asb + aoff[i]);
#pragma unroll
    for (int j = 0; j < 4; ++j) bfr[j] = *(const bf16x8*)(Bsb + boff[j]);
#pragma unroll
    for (int i = 0; i < 4; ++i)
#pragma unroll
      for (int j = 0; j < 4; ++j)
        acc[i][j] = __builtin_amdgcn_mfma_f32_16x16x32_bf16(afr[i], bfr[j], acc[i][j], 0, 0, 0);
  };

  // 2-phase pipeline, unrolled x2 (all K here have an even number of 32-steps)
  stage(As0, Bs0, 0);
  __syncthreads();
  for (int k0 = 0; k0 < K; k0 += 64) {
    if (k0 + 32 < K) stage(As1, Bs1, k0 + 32);
    compute(As0, Bs0);
    __syncthreads();
    if (k0 + 64 < K) stage(As0, Bs0, k0 + 64);
    compute(As1, Bs1);
    __syncthreads();
  }
  // after the final barrier the staging LDS is dead — reusable as epilogue scratch

  if (EPI == EPI_F32 || EPI == EPI_SPLITK_PART) {
    // coalesced f32 epilogue: per-wave 8 KB LDS transpose (wave-private, no
    // barriers). Scratch col XOR'd with quad<<4: write 2-way (free), read is
    // a lane-permutation (conflict-free). Store = 256B contiguous per row.
    float* scr = (float*)SMEM + wave * 2048;  // 32 rows x 64 cols f32
    float* outB = (EPI == EPI_SPLITK_PART)
        ? ((float*)Cout + (long long)z * M * ldc)
        : ((float*)Cout + cOff);
#pragma unroll
    for (int h = 0; h < 2; ++h) {
#pragma unroll
      for (int ii = 0; ii < 2; ++ii)
#pragma unroll
        for (int j = 0; j < 4; ++j) {
          const int lc = j * 16 + mf;
          float bv = 0.0f;
          if (EPI == EPI_SPLITK_PART && z == 0) bv = bias[n0 + wn + lc];
#pragma unroll
          for (int r = 0; r < 4; ++r)
            scr[(ii * 16 + quad * 4 + r) * 64 + (lc ^ (quad << 4))] =
                acc[2 * h + ii][j][r] + bv;
        }
      const long long row0 = m0 + wm + h * 32;
      const int gcol = n0 + wn + lane;
      if (gcol < N) {
#pragma unroll
        for (int t = 0; t < 32; ++t)
          outB[(row0 + t) * ldc + gcol] =
              scr[t * 64 + (lane ^ (((t >> 2) & 3) << 4))];
      }
    }
    return;
  }

#pragma unroll
  for (int j = 0; j < 4; ++j) {
    const int col = n0 + wn + j * 16 + mf;
    if (col >= N) continue;
    float bv = 0.0f;
    if (EPI == EPI_BF16_BIAS || EPI == EPI_BF16_BIAS_GELU || EPI == EPI_QKV)
      bv = bias[col];
    if (EPI == EPI_QKV && col >= 1536) {
      // V columns: write transposed into vT[(b*NH+h)*64+d][t], packed x4
      const int hd = col - 1536;
#pragma unroll
      for (int i = 0; i < 4; ++i) {
        const int t0 = m0 + wm + i * 16 + quad * 4;  // 4 consecutive t
        u16x4 pk;
#pragma unroll
        for (int r = 0; r < 4; ++r) pk[r] = f2bf(acc[i][j][r] + bv);
        const int b_ = t0 >> 10;
        const long long vi =
            ((long long)((b_ * NH + (hd >> 6)) * 64 + (hd & 63))) * 1024 + (t0 & 1023);
        *(u16x4*)(vtAux + vi) = pk;
      }
      continue;
    }
#pragma unroll
    for (int i = 0; i < 4; ++i) {
#pragma unroll
      for (int r = 0; r < 4; ++r) {
        const int row = m0 + wm + i * 16 + quad * 4 + r;
        float v = acc[i][j][r] + bv;
        if (EPI == EPI_BF16_BIAS_GELU) {
          // tanh-GELU via sigmoid identity: 0.5v(1+tanh(w)) = v*sigmoid(2w)
          const float u = v + 0.044715f * v * v * v;
          v = v / (1.0f + __expf(-1.5957691216057308f * u));
        }
        const long long ci = cOff + (long long)row * ldc + col;
        ((u16*)Cout)[ci] = f2bf(v);
      }
    }
  }
}

// ---------------------------------------------------------------- launch
extern "C" void kernel_launch(void* const* d_in, const int* in_sizes, int n_in,
                              void* d_out, int out_size, void* d_ws, size_t ws_size,
                              hipStream_t stream) {
  const int* tokens      = (const int*)d_in[0];
  const float* tok_embed = (const float*)d_in[1];
  const float* pos_embed = (const float*)d_in[2];
  const float* qkv_w     = (const float*)d_in[3];
  const float* qkv_b     = (const float*)d_in[4];
  const float* proj_w    = (const float*)d_in[5];
  const float* proj_b    = (const float*)d_in[6];
  const float* ln1_w     = (const float*)d_in[7];
  const float* ln1_b     = (const float*)d_in[8];
  const float* ln2_w     = (const float*)d_in[9];
  const float* ln2_b     = (const float*)d_in[10];
  const float* fc1_w     = (const float*)d_in[11];
  const float* fc1_b     = (const float*)d_in[12];
  const float* fc2_w     = (const float*)d_in[13];
  const float* fc2_b     = (const float*)d_in[14];
  const float* lnf_w     = (const float*)d_in[15];
  const float* lnf_b     = (const float*)d_in[16];

  if (ws_size < 440u * 1024u * 1024u) return;  // scratch guard

  char* p = (char*)d_ws;
  auto alloc = [&](size_t bytes) {
    void* r = (void*)p;
    p += (bytes + 255) & ~(size_t)255;
    return r;
  };
  u16* wq   = (u16*)alloc((size_t)NL * 2304 * 768 * 2);  // qkv_w^T  [L][2304][768]
  u16* wp   = (u16*)alloc((size_t)NL * 768 * 768 * 2);   // proj_w^T [L][768][768]
  u16* w1   = (u16*)alloc((size_t)NL * 3072 * 768 * 2);  // fc1_w^T  [L][3072][768]
  u16* w2   = (u16*)alloc((size_t)NL * 768 * 3072 * 2);  // fc2_w^T  [L][768][3072]
  u16* te   = (u16*)alloc((size_t)VOC * 768 * 2);        // tok_embed bf16 [V][768]
  float* x  = (float*)alloc((size_t)BT * 768 * 4);       // residual stream fp32
  u16* hbuf = (u16*)alloc((size_t)BT * 768 * 2);         // LN output bf16
  u16* qkv  = (u16*)alloc((size_t)BT * 2304 * 2);
  u16* vT   = (u16*)alloc((size_t)24 * 64 * 1024 * 2);   // [b,h][64][1024]
  u16* attn = (u16*)alloc((size_t)BT * 768 * 2);
  u16* ff   = (u16*)alloc((size_t)BT * 3072 * 2);
  u16* xf   = (u16*)alloc((size_t)BT * 768 * 2);
  float* pp = (float*)alloc((size_t)4 * BT * 768 * 4);   // split-K partials

  // weight conversion (per call; ws is re-poisoned before every timed launch)
  transpose_convert<<<dim3(2304 / 32, 768 / 32, NL), 256, 0, stream>>>(qkv_w, wq, 768, 2304);
  transpose_convert<<<dim3(768 / 32, 768 / 32, NL), 256, 0, stream>>>(proj_w, wp, 768, 768);
  transpose_convert<<<dim3(3072 / 32, 768 / 32, NL), 256, 0, stream>>>(fc1_w, w1, 768, 3072);
  transpose_convert<<<dim3(768 / 32, 3072 / 32, NL), 256, 0, stream>>>(fc2_w, w2, 3072, 768);
  convert_bf16<<<4096, 256, 0, stream>>>(tok_embed, te, (long long)VOC * 768);
  embed_kernel<<<BT, 256, 0, stream>>>(tokens, tok_embed, pos_embed, x);

  for (int l = 0; l < NL; ++l) {
    // ln1: fold previous layer's fc2 partials (4 slices) into x, then LN
    ln_sum<<<BT, 256, 0, stream>>>(x, pp, l == 0 ? 0 : 4,
                                   ln1_w + l * 768, ln1_b + l * 768, hbuf);
    // qkv GEMM; V columns (>=1536) go transposed straight into vT
    gemm_nt<EPI_QKV><<<dim3(2304 / 128, BT / 128, 1), 256, 0, stream>>>(
        hbuf, wq + (size_t)l * 2304 * 768, qkv_b + l * 2304, qkv, vT,
        BT, 2304, 768, 768, 768, 2304, 0, 0, 0, 0, 0, 0, 1, 0, 288 / 8, 1);
    // fused flash attention: QK^T + causal online-softmax + PV in one pass
    flash_attn<<<384, 256, 0, stream>>>(qkv, vT, attn);
    // proj: split-K x3 (288 blocks, full-chip), coalesced partial writes
    gemm_nt<EPI_SPLITK_PART><<<dim3(768 / 128, BT / 128, 3), 256, 0, stream>>>(
        attn, wp + (size_t)l * 768 * 768, proj_b + l * 768, pp, nullptr,
        BT, 768, 768, 768, 768, 768, 0, 0, 0, 0, 0, 0, 1, 0, 96 / 8, 3);
    // ln2: x += proj partials (3 slices), then LN
    ln_sum<<<BT, 256, 0, stream>>>(x, pp, 3,
                                   ln2_w + l * 768, ln2_b + l * 768, hbuf);
    gemm_nt<EPI_BF16_BIAS_GELU><<<dim3(3072 / 128, BT / 128, 1), 256, 0, stream>>>(
        hbuf, w1 + (size_t)l * 3072 * 768, fc1_b + l * 3072, ff, nullptr,
        BT, 3072, 768, 768, 768, 3072, 0, 0, 0, 0, 0, 0, 1, 0, 384 / 8, 1);
    // fc2: split-K x4 (384 blocks), coalesced partial writes
    gemm_nt<EPI_SPLITK_PART><<<dim3(768 / 128, BT / 128, 4), 256, 0, stream>>>(
        ff, w2 + (size_t)l * 768 * 3072, fc2_b + l * 768, pp, nullptr,
        BT, 768, 3072, 3072, 3072, 768, 0, 0, 0, 0, 0, 0, 1, 0, 96 / 8, 4);
  }
  // final LN folds the last fc2 partials
  ln_sum<<<BT, 256, 0, stream>>>(x, pp, 4, lnf_w, lnf_b, xf);
  // lm_head: 128x128 tile (16x393 grid), M fastest + chunked XCD swizzle,
  // coalesced LDS-transposed epilogue (6288 % 8 == 0)
  gemm_nt<EPI_F32><<<dim3(BT / 128, (VOC + 127) / 128, 1), 256, 0, stream>>>(
      xf, te, nullptr, (float*)d_out, nullptr,
      BT, VOC, 768, 768, 768, VOC, 0, 0, 0, 0, 0, 0, 1, 1, 6288 / 8, 1);
}